// Round 10
// baseline (74.021 us; speedup 1.0000x reference)
//
#include <hip/hip_runtime.h>
#include <hip/hip_bf16.h>
#include <math.h>

// Problem constants
#define B_  8
#define T_  2048
#define C_  128
#define H_  4
#define DH_ 32
#define BH_ 32
#define NTOK 16384
// (1/sqrt(32)) * log2(e): scores come out in log2 domain -> softmax via exp2
#define QSCALE_ 0.25503486f

typedef __attribute__((ext_vector_type(8))) __bf16 bfrag;        // 4 VGPRs, MFMA A/B
typedef __attribute__((ext_vector_type(4))) float f32x4;
typedef __attribute__((ext_vector_type(16))) float f32x16;       // 32x32 MFMA C/D
typedef __attribute__((ext_vector_type(2))) unsigned int u32x2;
typedef __attribute__((ext_vector_type(4))) unsigned int u32x4;

__device__ __forceinline__ unsigned int pack2bf(float a, float b) {
    unsigned int ua = __float_as_uint(a);
    unsigned int ub = __float_as_uint(b);
    ua += 0x7fffu + ((ua >> 16) & 1u);   // RNE to bf16
    ub += 0x7fffu + ((ub >> 16) & 1u);
    return (ua >> 16) | (ub & 0xffff0000u);
}

// single-instruction packed f32x2 -> bf16x2 (RNE; no builtin on gfx950)
__device__ __forceinline__ unsigned int cvtpk_bf16(float lo, float hi) {
    unsigned int r;
    asm("v_cvt_pk_bf16_f32 %0, %1, %2" : "=v"(r) : "v"(lo), "v"(hi));
    return r;
}

// raw v_exp_f32 (2^x)
__device__ __forceinline__ float fast_exp2(float x) {
    float r;
    asm("v_exp_f32 %0, %1" : "=v"(r) : "v"(x));
    return r;
}

// ---------------------------------------------------------------------------
// Kernel 0: prep — transpose Wqkv -> WqkvT bf16 [384][128]; Wout -> WoutT
// bf16 [128][128]. 32 blocks.
// ---------------------------------------------------------------------------
__global__ __launch_bounds__(256)
void prep(const float* __restrict__ Wqkv, const float* __restrict__ Wout,
          __hip_bfloat16* __restrict__ WqkvT, __hip_bfloat16* __restrict__ WoutT) {
    const int bid = blockIdx.x;
    const int tid = threadIdx.x;
    if (bid < 24) {
        const int idx = bid * 256 + tid;             // 0..6143
        const int n = idx >> 4, k8 = idx & 15;
        float v[8];
#pragma unroll
        for (int i = 0; i < 8; ++i) v[i] = Wqkv[(k8 * 8 + i) * 384 + n];
        u32x4 pk;
        pk.x = pack2bf(v[0], v[1]); pk.y = pack2bf(v[2], v[3]);
        pk.z = pack2bf(v[4], v[5]); pk.w = pack2bf(v[6], v[7]);
        *(u32x4*)(WqkvT + n * 128 + k8 * 8) = pk;
    } else {
        const int idx = (bid - 24) * 256 + tid;      // 0..2047
        const int n = idx >> 4, k8 = idx & 15;
        float v[8];
#pragma unroll
        for (int i = 0; i < 8; ++i) v[i] = Wout[(k8 * 8 + i) * 128 + n];
        u32x4 pk;
        pk.x = pack2bf(v[0], v[1]); pk.y = pack2bf(v[2], v[3]);
        pk.z = pack2bf(v[4], v[5]); pk.w = pack2bf(v[6], v[7]);
        *(u32x4*)(WoutT + n * 128 + k8 * 8) = pk;
    }
}

// ---------------------------------------------------------------------------
// Kernel 1: MFMA QKV projection; reads fp32 x directly (cvt_pk to bf16 frags).
// Q/K (j<4): swapped mfma(wf,xf) -> lane owns token -> 8B store.
// V (j>=4): mfma(xf,wf) -> lane owns col d, regs = 4 consecutive tokens ->
// 8B store into TILED Vt[bh][u][32d][32s] (2KB-contiguous per 32-s unit).
// ---------------------------------------------------------------------------
__global__ __launch_bounds__(256)
void qkv_mfma(const float* __restrict__ x,
              const __hip_bfloat16* __restrict__ WT,
              const float* __restrict__ bqkv,
              __hip_bfloat16* __restrict__ Qb, __hip_bfloat16* __restrict__ Kb,
              __hip_bfloat16* __restrict__ Vt) {
    const int mbase = blockIdx.x * 16;
    const int w = threadIdx.x >> 6, lane = threadIdx.x & 63;
    const int qi = lane & 15, grp = lane >> 4;

    const f32x4 zero = {0.f, 0.f, 0.f, 0.f};
    f32x4 acc[6] = {zero, zero, zero, zero, zero, zero};

    const float* xrow = x + (size_t)(mbase + qi) * 128;
    bfrag xf[4];
#pragma unroll
    for (int ks = 0; ks < 4; ++ks) {
        const float4 a = *(const float4*)(xrow + ks * 32 + grp * 8);
        const float4 b = *(const float4*)(xrow + ks * 32 + grp * 8 + 4);
        u32x4 pk;
        pk.x = cvtpk_bf16(a.x, a.y);
        pk.y = cvtpk_bf16(a.z, a.w);
        pk.z = cvtpk_bf16(b.x, b.y);
        pk.w = cvtpk_bf16(b.z, b.w);
        xf[ks] = __builtin_bit_cast(bfrag, pk);
    }

#pragma unroll
    for (int j = 0; j < 6; ++j) {
        const int nb = j * 4 + w;
#pragma unroll
        for (int ks = 0; ks < 4; ++ks) {
            const bfrag wf = *(const bfrag*)(WT + (size_t)(nb * 16 + qi) * 128 + ks * 32 + grp * 8);
            if (j < 4) acc[j] = __builtin_amdgcn_mfma_f32_16x16x32_bf16(wf, xf[ks], acc[j], 0, 0, 0);
            else       acc[j] = __builtin_amdgcn_mfma_f32_16x16x32_bf16(xf[ks], wf, acc[j], 0, 0, 0);
        }
    }

    const long bb = mbase >> 11;        // batch
    const long tloc = mbase & 2047;     // token within batch

    // Q/K: lane owns token t = tloc+qi, regs are cols c0..c0+3
#pragma unroll
    for (int j = 0; j < 4; ++j) {
        const int nb = j * 4 + w;
        const int c0 = nb * 16 + grp * 4;
        const float4 bias = *(const float4*)&bqkv[c0];
        const int local = c0 & 127;
        const int h = local >> 5, d0 = local & 31;
        __hip_bfloat16* dst = (j < 2) ? Qb : Kb;
        const float sc = (j < 2) ? QSCALE_ : 1.f;
        const long t = tloc + qi;
        u32x2 pw;
        pw.x = pack2bf((acc[j][0] + bias.x) * sc, (acc[j][1] + bias.y) * sc);
        pw.y = pack2bf((acc[j][2] + bias.z) * sc, (acc[j][3] + bias.w) * sc);
        *(u32x2*)&dst[((bb * H_ + h) * T_ + t) * DH_ + d0] = pw;
    }
    // V: lane owns col c, regs are tokens tloc+grp*4 .. +3 (same 32-unit)
#pragma unroll
    for (int j = 4; j < 6; ++j) {
        const int nb = j * 4 + w;
        const int c = nb * 16 + qi;
        const int local = c - 256;
        const int h = local >> 5, d = local & 31;
        const float bias = bqkv[c];
        const long t0 = tloc + grp * 4;
        const long u = t0 >> 5;
        const long sin = t0 & 31;
        u32x2 pw;
        pw.x = pack2bf(acc[j][0] + bias, acc[j][1] + bias);
        pw.y = pack2bf(acc[j][2] + bias, acc[j][3] + bias);
        *(u32x2*)&Vt[(((bb * H_ + h) * 64 + u) * 32 + d) * 32 + sin] = pw;
    }
}

// ---------------------------------------------------------------------------
// Kernel 2: FUSED flash attention + output projection.
// Block = (b, chunk c of 32 tokens); 4 waves = 4 heads, each wave runs its
// head's full s-range (units 0..c), fixed-max softmax, in-register P path.
// Then one __syncthreads: normalized head outputs (bf16) assembled in LDS
// Osm[32 tok][128 dims], and each wave computes a 32x32 tile of the final
// out = Osm @ Wout + bout (8 more MFMAs). No Ob global round-trip.
// Grid 512 = 8 b (XCD-aligned) x 64 chunks, heavy chunks first.
// ---------------------------------------------------------------------------
__global__ __launch_bounds__(256)
void attn_out(const __hip_bfloat16* __restrict__ Qb,
              const __hip_bfloat16* __restrict__ Kb,
              const __hip_bfloat16* __restrict__ Vt,
              const __hip_bfloat16* __restrict__ WoutT,
              const float* __restrict__ bout, float* __restrict__ out) {
    __shared__ unsigned int Osm[32][68];   // bf16-pair rows, 272B stride (16B-aligned)

    const int lin = blockIdx.x;           // 0..511
    const int b   = lin & 7;              // = XCD under round-robin dispatch
    const int c   = 63 - (lin >> 3);      // heavy chunks dispatched first

    const int w    = threadIdx.x >> 6;    // head
    const int lane = threadIdx.x & 63;
    const int ql   = lane & 31;
    const int hi   = lane >> 5;
    const int hi4  = hi * 4;
    const int hi8  = hi * 8;

    const int bh = b * H_ + w;
    const int q  = c * 32 + ql;

    const __hip_bfloat16* Qp = Qb + (size_t)bh * T_ * DH_;
    const __hip_bfloat16* Kp = Kb + (size_t)bh * T_ * DH_;
    const __hip_bfloat16* Vp = Vt + (size_t)bh * 64 * 1024;   // tiled [u][32d][32s]

    const bfrag qf0 = *(const bfrag*)(Qp + q * DH_ + hi8);
    const bfrag qf1 = *(const bfrag*)(Qp + q * DH_ + 16 + hi8);

    f32x16 o;
#pragma unroll
    for (int r = 0; r < 16; ++r) o[r] = 0.f;
    float l = 0.f;

    auto ldK = [&](int u, bfrag& k0, bfrag& k1, bfrag& v0, bfrag& v1) {
        k0 = *(const bfrag*)(Kp + (u * 32 + ql) * DH_ + hi8);
        k1 = *(const bfrag*)(Kp + (u * 32 + ql) * DH_ + 16 + hi8);
        const __hip_bfloat16* vb = Vp + u * 1024 + ql * 32;
        v0 = *(const bfrag*)(vb + hi8);
        v1 = *(const bfrag*)(vb + 16 + hi8);
    };

    auto proc = [&](const bfrag& kf0, const bfrag& kf1, const bfrag& vf0,
                    const bfrag& vf1, int sbase, bool band) {
        f32x16 s;
#pragma unroll
        for (int r = 0; r < 16; ++r) s[r] = 0.f;
        s = __builtin_amdgcn_mfma_f32_32x32x16_bf16(kf0, qf0, s, 0, 0, 0);
        s = __builtin_amdgcn_mfma_f32_32x32x16_bf16(kf1, qf1, s, 0, 0, 0);
        if (band) {
#pragma unroll
            for (int r = 0; r < 16; ++r) {
                const int srow = sbase + (r & 3) + 8 * (r >> 2) + hi4;
                if (srow > q) s[r] = -INFINITY;
            }
        }
#pragma unroll
        for (int r = 0; r < 16; ++r) { s[r] = fast_exp2(s[r]); l += s[r]; }
        u32x4 w0, w1;
        {
            unsigned a0 = cvtpk_bf16(s[0], s[1]);
            unsigned a1 = cvtpk_bf16(s[2], s[3]);
            unsigned a2 = cvtpk_bf16(s[4], s[5]);
            unsigned a3 = cvtpk_bf16(s[6], s[7]);
            auto r02 = __builtin_amdgcn_permlane32_swap((int)a0, (int)a2, false, false);
            auto r13 = __builtin_amdgcn_permlane32_swap((int)a1, (int)a3, false, false);
            w0.x = (unsigned)r02[0]; w0.y = (unsigned)r13[0];
            w0.z = (unsigned)r02[1]; w0.w = (unsigned)r13[1];
        }
        {
            unsigned a0 = cvtpk_bf16(s[8],  s[9]);
            unsigned a1 = cvtpk_bf16(s[10], s[11]);
            unsigned a2 = cvtpk_bf16(s[12], s[13]);
            unsigned a3 = cvtpk_bf16(s[14], s[15]);
            auto r02 = __builtin_amdgcn_permlane32_swap((int)a0, (int)a2, false, false);
            auto r13 = __builtin_amdgcn_permlane32_swap((int)a1, (int)a3, false, false);
            w1.x = (unsigned)r02[0]; w1.y = (unsigned)r13[0];
            w1.z = (unsigned)r02[1]; w1.w = (unsigned)r13[1];
        }
        o = __builtin_amdgcn_mfma_f32_32x32x16_bf16(
                vf0, __builtin_bit_cast(bfrag, w0), o, 0, 0, 0);
        o = __builtin_amdgcn_mfma_f32_32x32x16_bf16(
                vf1, __builtin_bit_cast(bfrag, w1), o, 0, 0, 0);
    };

    // ---- attention over units 0..c with 2-deep ping-pong prefetch
    bfrag ck0, ck1, cv0, cv1, nk0, nk1, nv0, nv1;
    ldK(0, ck0, ck1, cv0, cv1);
    for (int u = 0; u <= c; ++u) {
        if (u + 1 <= c) ldK(u + 1, nk0, nk1, nv0, nv1);
        proc(ck0, ck1, cv0, cv1, u * 32, u == c);
        ck0 = nk0; ck1 = nk1; cv0 = nv0; cv1 = nv1;
    }

    // merge the two hi-halves' l (same q, disjoint s rows)
    l += __shfl_xor(l, 32);
    const float rl = 1.f / l;

    // ---- deposit normalized bf16 head-output into Osm[q][128]
#pragma unroll
    for (int pi = 0; pi < 8; ++pi) {
        const int r = pi * 2;
        const int n = (r & 3) + 8 * (r >> 2) + hi4;      // dim within head
        Osm[ql][(w * 32 + n) >> 1] = cvtpk_bf16(o[r] * rl, o[r + 1] * rl);
    }
    __syncthreads();

    // ---- output projection: wave w computes cols w*32..+31 for 32 tokens
    f32x16 acc;
#pragma unroll
    for (int r = 0; r < 16; ++r) acc[r] = 0.f;
#pragma unroll
    for (int ks = 0; ks < 8; ++ks) {
        const bfrag wf = *(const bfrag*)(WoutT + (size_t)(w * 32 + ql) * 128 + ks * 16 + hi8);
        const u32x4 ofu = *(const u32x4*)&Osm[ql][ks * 8 + hi4];
        acc = __builtin_amdgcn_mfma_f32_32x32x16_bf16(
                  wf, __builtin_bit_cast(bfrag, ofu), acc, 0, 0, 0);
    }

    float* orow = out + ((size_t)b * T_ + c * 32 + ql) * 128 + w * 32;
#pragma unroll
    for (int pi = 0; pi < 8; ++pi) {
        const int r = pi * 2;
        const int n = (r & 3) + 8 * (r >> 2) + hi4;
        const float2 bb2 = *(const float2*)&bout[w * 32 + n];
        float2 ov;
        ov.x = acc[r] + bb2.x;
        ov.y = acc[r + 1] + bb2.y;
        *(float2*)&orow[n] = ov;
    }
}

// ---------------------------------------------------------------------------
extern "C" void kernel_launch(void* const* d_in, const int* in_sizes, int n_in,
                              void* d_out, int out_size, void* d_ws, size_t ws_size,
                              hipStream_t stream) {
    const float* x    = (const float*)d_in[0];
    const float* Wqkv = (const float*)d_in[1];
    const float* bqkv = (const float*)d_in[2];
    const float* Wout = (const float*)d_in[3];
    const float* bout = (const float*)d_in[4];
    float* out = (float*)d_out;

    const size_t per = (size_t)BH_ * T_ * DH_;   // 2,097,152 bf16 elems = 4 MB
    __hip_bfloat16* Qb    = (__hip_bfloat16*)d_ws;
    __hip_bfloat16* Kb    = Qb + per;
    __hip_bfloat16* Vt    = Kb + per;
    __hip_bfloat16* WqkvT = Vt + per;
    __hip_bfloat16* WoutT = WqkvT + 384 * 128;

    prep<<<32, 256, 0, stream>>>(Wqkv, Wout, WqkvT, WoutT);

    qkv_mfma<<<NTOK / 16, 256, 0, stream>>>(x, WqkvT, bqkv, Qb, Kb, Vt);

    attn_out<<<512, 256, 0, stream>>>(Qb, Kb, Vt, WoutT, bout, out);
}

// Round 11
// 55.480 us; speedup vs baseline: 1.3342x; 1.3342x over previous
//
#include <hip/hip_runtime.h>
#include <hip/hip_bf16.h>
#include <math.h>

// Problem constants
#define B_  8
#define T_  2048
#define C_  128
#define H_  4
#define DH_ 32
#define BH_ 32
#define NTOK 16384
// (1/sqrt(32)) * log2(e): scores come out in log2 domain -> softmax via exp2
#define QSCALE_ 0.25503486f

typedef __attribute__((ext_vector_type(8))) __bf16 bfrag;        // 4 VGPRs, MFMA A/B
typedef __attribute__((ext_vector_type(4))) float f32x4;
typedef __attribute__((ext_vector_type(16))) float f32x16;       // 32x32 MFMA C/D
typedef __attribute__((ext_vector_type(2))) unsigned int u32x2;
typedef __attribute__((ext_vector_type(4))) unsigned int u32x4;

__device__ __forceinline__ unsigned int pack2bf(float a, float b) {
    unsigned int ua = __float_as_uint(a);
    unsigned int ub = __float_as_uint(b);
    ua += 0x7fffu + ((ua >> 16) & 1u);   // RNE to bf16
    ub += 0x7fffu + ((ub >> 16) & 1u);
    return (ua >> 16) | (ub & 0xffff0000u);
}

// single-instruction packed f32x2 -> bf16x2 (RNE; no builtin on gfx950)
__device__ __forceinline__ unsigned int cvtpk_bf16(float lo, float hi) {
    unsigned int r;
    asm("v_cvt_pk_bf16_f32 %0, %1, %2" : "=v"(r) : "v"(lo), "v"(hi));
    return r;
}

// raw v_exp_f32 (2^x)
__device__ __forceinline__ float fast_exp2(float x) {
    float r;
    asm("v_exp_f32 %0, %1" : "=v"(r) : "v"(x));
    return r;
}

// ---------------------------------------------------------------------------
// Kernel 0: prep — transpose Wqkv -> WqkvT bf16 [384][128]; Wout -> WoutT
// bf16 [128][128]. 32 blocks.
// ---------------------------------------------------------------------------
__global__ __launch_bounds__(256)
void prep(const float* __restrict__ Wqkv, const float* __restrict__ Wout,
          __hip_bfloat16* __restrict__ WqkvT, __hip_bfloat16* __restrict__ WoutT) {
    const int bid = blockIdx.x;
    const int tid = threadIdx.x;
    if (bid < 24) {
        const int idx = bid * 256 + tid;             // 0..6143
        const int n = idx >> 4, k8 = idx & 15;
        float v[8];
#pragma unroll
        for (int i = 0; i < 8; ++i) v[i] = Wqkv[(k8 * 8 + i) * 384 + n];
        u32x4 pk;
        pk.x = pack2bf(v[0], v[1]); pk.y = pack2bf(v[2], v[3]);
        pk.z = pack2bf(v[4], v[5]); pk.w = pack2bf(v[6], v[7]);
        *(u32x4*)(WqkvT + n * 128 + k8 * 8) = pk;
    } else {
        const int idx = (bid - 24) * 256 + tid;      // 0..2047
        const int n = idx >> 4, k8 = idx & 15;
        float v[8];
#pragma unroll
        for (int i = 0; i < 8; ++i) v[i] = Wout[(k8 * 8 + i) * 128 + n];
        u32x4 pk;
        pk.x = pack2bf(v[0], v[1]); pk.y = pack2bf(v[2], v[3]);
        pk.z = pack2bf(v[4], v[5]); pk.w = pack2bf(v[6], v[7]);
        *(u32x4*)(WoutT + n * 128 + k8 * 8) = pk;
    }
}

// ---------------------------------------------------------------------------
// Kernel 1: MFMA QKV projection; reads fp32 x directly (cvt_pk to bf16 frags).
// Q/K (j<4): swapped mfma(wf,xf) -> lane owns token -> 8B store.
// V (j>=4): mfma(xf,wf) -> lane owns col d, regs = 4 consecutive tokens ->
// 8B store into TILED Vt[bh][u][32d][32s] (2KB-contiguous per 32-s unit).
// ---------------------------------------------------------------------------
__global__ __launch_bounds__(256)
void qkv_mfma(const float* __restrict__ x,
              const __hip_bfloat16* __restrict__ WT,
              const float* __restrict__ bqkv,
              __hip_bfloat16* __restrict__ Qb, __hip_bfloat16* __restrict__ Kb,
              __hip_bfloat16* __restrict__ Vt) {
    const int mbase = blockIdx.x * 16;
    const int w = threadIdx.x >> 6, lane = threadIdx.x & 63;
    const int qi = lane & 15, grp = lane >> 4;

    const f32x4 zero = {0.f, 0.f, 0.f, 0.f};
    f32x4 acc[6] = {zero, zero, zero, zero, zero, zero};

    const float* xrow = x + (size_t)(mbase + qi) * 128;
    bfrag xf[4];
#pragma unroll
    for (int ks = 0; ks < 4; ++ks) {
        const float4 a = *(const float4*)(xrow + ks * 32 + grp * 8);
        const float4 b = *(const float4*)(xrow + ks * 32 + grp * 8 + 4);
        u32x4 pk;
        pk.x = cvtpk_bf16(a.x, a.y);
        pk.y = cvtpk_bf16(a.z, a.w);
        pk.z = cvtpk_bf16(b.x, b.y);
        pk.w = cvtpk_bf16(b.z, b.w);
        xf[ks] = __builtin_bit_cast(bfrag, pk);
    }

#pragma unroll
    for (int j = 0; j < 6; ++j) {
        const int nb = j * 4 + w;
#pragma unroll
        for (int ks = 0; ks < 4; ++ks) {
            const bfrag wf = *(const bfrag*)(WT + (size_t)(nb * 16 + qi) * 128 + ks * 32 + grp * 8);
            if (j < 4) acc[j] = __builtin_amdgcn_mfma_f32_16x16x32_bf16(wf, xf[ks], acc[j], 0, 0, 0);
            else       acc[j] = __builtin_amdgcn_mfma_f32_16x16x32_bf16(xf[ks], wf, acc[j], 0, 0, 0);
        }
    }

    const long bb = mbase >> 11;        // batch
    const long tloc = mbase & 2047;     // token within batch

    // Q/K: lane owns token t = tloc+qi, regs are cols c0..c0+3
#pragma unroll
    for (int j = 0; j < 4; ++j) {
        const int nb = j * 4 + w;
        const int c0 = nb * 16 + grp * 4;
        const float4 bias = *(const float4*)&bqkv[c0];
        const int local = c0 & 127;
        const int h = local >> 5, d0 = local & 31;
        __hip_bfloat16* dst = (j < 2) ? Qb : Kb;
        const float sc = (j < 2) ? QSCALE_ : 1.f;
        const long t = tloc + qi;
        u32x2 pw;
        pw.x = pack2bf((acc[j][0] + bias.x) * sc, (acc[j][1] + bias.y) * sc);
        pw.y = pack2bf((acc[j][2] + bias.z) * sc, (acc[j][3] + bias.w) * sc);
        *(u32x2*)&dst[((bb * H_ + h) * T_ + t) * DH_ + d0] = pw;
    }
    // V: lane owns col c, regs are tokens tloc+grp*4 .. +3 (same 32-unit)
#pragma unroll
    for (int j = 4; j < 6; ++j) {
        const int nb = j * 4 + w;
        const int c = nb * 16 + qi;
        const int local = c - 256;
        const int h = local >> 5, d = local & 31;
        const float bias = bqkv[c];
        const long t0 = tloc + grp * 4;
        const long u = t0 >> 5;
        const long sin = t0 & 31;
        u32x2 pw;
        pw.x = pack2bf(acc[j][0] + bias, acc[j][1] + bias);
        pw.y = pack2bf(acc[j][2] + bias, acc[j][3] + bias);
        *(u32x2*)&Vt[(((bb * H_ + h) * 64 + u) * 32 + d) * 32 + sin] = pw;
    }
}

// ---------------------------------------------------------------------------
// Kernel 2: FUSED flash attention + output projection, 8 waves/block.
// Block = (b, chunk c of 32 tokens); wave (h, e) = head h, s-units of
// parity e (u = e, e+2, ... <= c). Fixed-max softmax -> parity partials
// (o, l) combine by plain sum in LDS (1 barrier). e=0 waves then deposit
// normalized bf16 output into Osm and run the 128x128 out-projection.
// Grid 512 ordered so blocks k and k+256 have complementary c (65 units
// per CU under round-robin dispatch); 4 waves/SIMD via launch_bounds.
// ---------------------------------------------------------------------------
__global__ __launch_bounds__(512, 4)
void attn_out(const __hip_bfloat16* __restrict__ Qb,
              const __hip_bfloat16* __restrict__ Kb,
              const __hip_bfloat16* __restrict__ Vt,
              const __hip_bfloat16* __restrict__ WoutT,
              const float* __restrict__ bout, float* __restrict__ out) {
    __shared__ float csm[4][64][17];       // parity-1 partials (17.4 KB)
    __shared__ unsigned int Osm[32][68];   // bf16-pair rows (8.7 KB)

    const int lin = blockIdx.x;            // 0..511
    int b, c;
    if (lin < 256) { b = lin & 7; c = 63 - (lin >> 3); }   // heavy half
    else { const int m = lin - 256; b = m & 7; c = m >> 3; } // light half

    const int w    = threadIdx.x >> 6;     // 0..7
    const int h    = w & 3;                // head
    const int e    = w >> 2;               // s-parity
    const int lane = threadIdx.x & 63;
    const int ql   = lane & 31;
    const int hi   = lane >> 5;
    const int hi4  = hi * 4;
    const int hi8  = hi * 8;

    const int bh = b * H_ + h;
    const int q  = c * 32 + ql;

    const __hip_bfloat16* Qp = Qb + (size_t)bh * T_ * DH_;
    const __hip_bfloat16* Kp = Kb + (size_t)bh * T_ * DH_;
    const __hip_bfloat16* Vp = Vt + (size_t)bh * 64 * 1024;   // tiled [u][32d][32s]

    const bfrag qf0 = *(const bfrag*)(Qp + q * DH_ + hi8);
    const bfrag qf1 = *(const bfrag*)(Qp + q * DH_ + 16 + hi8);

    f32x16 o;
#pragma unroll
    for (int r = 0; r < 16; ++r) o[r] = 0.f;
    float l = 0.f;

    auto ldK = [&](int u, bfrag& k0, bfrag& k1, bfrag& v0, bfrag& v1) {
        k0 = *(const bfrag*)(Kp + (u * 32 + ql) * DH_ + hi8);
        k1 = *(const bfrag*)(Kp + (u * 32 + ql) * DH_ + 16 + hi8);
        const __hip_bfloat16* vb = Vp + u * 1024 + ql * 32;
        v0 = *(const bfrag*)(vb + hi8);
        v1 = *(const bfrag*)(vb + 16 + hi8);
    };

    auto proc = [&](const bfrag& kf0, const bfrag& kf1, const bfrag& vf0,
                    const bfrag& vf1, int sbase, bool band) {
        f32x16 s;
#pragma unroll
        for (int r = 0; r < 16; ++r) s[r] = 0.f;
        s = __builtin_amdgcn_mfma_f32_32x32x16_bf16(kf0, qf0, s, 0, 0, 0);
        s = __builtin_amdgcn_mfma_f32_32x32x16_bf16(kf1, qf1, s, 0, 0, 0);
        if (band) {
#pragma unroll
            for (int r = 0; r < 16; ++r) {
                const int srow = sbase + (r & 3) + 8 * (r >> 2) + hi4;
                if (srow > q) s[r] = -INFINITY;
            }
        }
#pragma unroll
        for (int r = 0; r < 16; ++r) { s[r] = fast_exp2(s[r]); l += s[r]; }
        u32x4 w0, w1;
        {
            unsigned a0 = cvtpk_bf16(s[0], s[1]);
            unsigned a1 = cvtpk_bf16(s[2], s[3]);
            unsigned a2 = cvtpk_bf16(s[4], s[5]);
            unsigned a3 = cvtpk_bf16(s[6], s[7]);
            auto r02 = __builtin_amdgcn_permlane32_swap((int)a0, (int)a2, false, false);
            auto r13 = __builtin_amdgcn_permlane32_swap((int)a1, (int)a3, false, false);
            w0.x = (unsigned)r02[0]; w0.y = (unsigned)r13[0];
            w0.z = (unsigned)r02[1]; w0.w = (unsigned)r13[1];
        }
        {
            unsigned a0 = cvtpk_bf16(s[8],  s[9]);
            unsigned a1 = cvtpk_bf16(s[10], s[11]);
            unsigned a2 = cvtpk_bf16(s[12], s[13]);
            unsigned a3 = cvtpk_bf16(s[14], s[15]);
            auto r02 = __builtin_amdgcn_permlane32_swap((int)a0, (int)a2, false, false);
            auto r13 = __builtin_amdgcn_permlane32_swap((int)a1, (int)a3, false, false);
            w1.x = (unsigned)r02[0]; w1.y = (unsigned)r13[0];
            w1.z = (unsigned)r02[1]; w1.w = (unsigned)r13[1];
        }
        o = __builtin_amdgcn_mfma_f32_32x32x16_bf16(
                vf0, __builtin_bit_cast(bfrag, w0), o, 0, 0, 0);
        o = __builtin_amdgcn_mfma_f32_32x32x16_bf16(
                vf1, __builtin_bit_cast(bfrag, w1), o, 0, 0, 0);
    };

    // ---- attention over units u = e, e+2, ... <= c (2-deep ping-pong)
    if (e <= c) {
        bfrag ck0, ck1, cv0, cv1, nk0, nk1, nv0, nv1;
        ldK(e, ck0, ck1, cv0, cv1);
        for (int u = e; u <= c; u += 2) {
            if (u + 2 <= c) ldK(u + 2, nk0, nk1, nv0, nv1);
            proc(ck0, ck1, cv0, cv1, u * 32, u == c);
            ck0 = nk0; ck1 = nk1; cv0 = nv0; cv1 = nv1;
        }
    }

    // merge the two hi-halves' l (same q, disjoint s rows)
    l += __shfl_xor(l, 32);

    // ---- parity combine (fixed-max softmax -> plain sums)
    if (e == 1) {
        float* my = &csm[h][lane][0];
        f32x4 t0 = {o[0], o[1], o[2], o[3]};
        f32x4 t1 = {o[4], o[5], o[6], o[7]};
        f32x4 t2 = {o[8], o[9], o[10], o[11]};
        f32x4 t3 = {o[12], o[13], o[14], o[15]};
        *(f32x4*)(my + 0) = t0;  *(f32x4*)(my + 4) = t1;
        *(f32x4*)(my + 8) = t2;  *(f32x4*)(my + 12) = t3;
        my[16] = l;
    }
    __syncthreads();
    if (e == 0) {
        const float* pr = &csm[h][lane][0];
#pragma unroll
        for (int r = 0; r < 16; ++r) o[r] += pr[r];
        l += pr[16];
        const float rl = 1.f / l;
        // deposit normalized bf16 head-output into Osm[token][128]
#pragma unroll
        for (int pi = 0; pi < 8; ++pi) {
            const int r = pi * 2;
            const int n = (r & 3) + 8 * (r >> 2) + hi4;      // dim within head
            Osm[ql][(h * 32 + n) >> 1] = cvtpk_bf16(o[r] * rl, o[r + 1] * rl);
        }
    }
    __syncthreads();

    // ---- output projection by the 4 e==0 waves: wave h -> cols h*32..+31
    if (e == 0) {
        f32x16 acc;
#pragma unroll
        for (int r = 0; r < 16; ++r) acc[r] = 0.f;
#pragma unroll
        for (int ks = 0; ks < 8; ++ks) {
            const bfrag wf = *(const bfrag*)(WoutT + (size_t)(h * 32 + ql) * 128 + ks * 16 + hi8);
            const u32x4 ofu = *(const u32x4*)&Osm[ql][ks * 8 + hi4];
            acc = __builtin_amdgcn_mfma_f32_32x32x16_bf16(
                      wf, __builtin_bit_cast(bfrag, ofu), acc, 0, 0, 0);
        }
        float* orow = out + ((size_t)b * T_ + c * 32 + ql) * 128 + h * 32;
#pragma unroll
        for (int pi = 0; pi < 8; ++pi) {
            const int r = pi * 2;
            const int n = (r & 3) + 8 * (r >> 2) + hi4;
            const float2 bb2 = *(const float2*)&bout[h * 32 + n];
            float2 ov;
            ov.x = acc[r] + bb2.x;
            ov.y = acc[r + 1] + bb2.y;
            *(float2*)&orow[n] = ov;
        }
    }
}

// ---------------------------------------------------------------------------
extern "C" void kernel_launch(void* const* d_in, const int* in_sizes, int n_in,
                              void* d_out, int out_size, void* d_ws, size_t ws_size,
                              hipStream_t stream) {
    const float* x    = (const float*)d_in[0];
    const float* Wqkv = (const float*)d_in[1];
    const float* bqkv = (const float*)d_in[2];
    const float* Wout = (const float*)d_in[3];
    const float* bout = (const float*)d_in[4];
    float* out = (float*)d_out;

    const size_t per = (size_t)BH_ * T_ * DH_;   // 2,097,152 bf16 elems = 4 MB
    __hip_bfloat16* Qb    = (__hip_bfloat16*)d_ws;
    __hip_bfloat16* Kb    = Qb + per;
    __hip_bfloat16* Vt    = Kb + per;
    __hip_bfloat16* WqkvT = Vt + per;
    __hip_bfloat16* WoutT = WqkvT + 384 * 128;

    prep<<<32, 256, 0, stream>>>(Wqkv, Wout, WqkvT, WoutT);

    qkv_mfma<<<NTOK / 16, 256, 0, stream>>>(x, WqkvT, bqkv, Qb, Kb, Vt);

    attn_out<<<512, 512, 0, stream>>>(Qb, Kb, Vt, WoutT, bout, out);
}